// Round 1
// baseline (172.508 us; speedup 1.0000x reference)
//
#include <hip/hip_runtime.h>
#include <math.h>

static constexpr int kBS  = 512;
static constexpr int kL   = 68;
static constexpr int kIMG = 224;
static constexpr int kR2  = 49;
static constexpr int kLL  = kL * kL;     // 4624
static constexpr int kG4  = kLL / 4;     // 1156 float4 groups per batch

// jnp.linspace(-3.5,3.5,7)[k]/224*2 — JAX convex-combination linspace,
// exact op order, no contraction. k=6: step=1.0 -> exactly 3.5.
__device__ __forceinline__ float lin_off(int k) {
  float step = __fdiv_rn((float)k, 6.0f);
  float a = __fmul_rn(-3.5f, __fsub_rn(1.0f, step));
  float b = __fmul_rn(3.5f, step);
  float x = __fadd_rn(a, b);
  return __fmul_rn(__fdiv_rn(x, 224.0f), 2.0f);
}

// One block per batch (512 blocks x 1024 threads = 16 waves).
// Phase 1: each wave computes region medians for l = wave, wave+16, ...
//          identical per-lane fp sequence to the old k_median (bitonic
//          64-lane sort + ballot count -> k-th order statistic). The 7-entry
//          linspace table is computed by lanes 0-6 with the exact old op
//          sequence and shfl-broadcast (bit-identical values).
// Phase 2: median-of-medians rank (identical compare sequence to old k_out).
// Phase 3: 4624 outputs as 1156 float4 groups (float4 stores) + masked
//          smooth-L1 partials in double -> one (num,den) pair per batch.
__global__ __launch_bounds__(1024) void k_fused(
    const float* __restrict__ depth, const float* __restrict__ lmk,
    const float* __restrict__ scale, const float* __restrict__ bbox,
    const float* __restrict__ rdp,
    float* __restrict__ out_diff, float* __restrict__ out_mask,
    double* __restrict__ part) {
  __shared__ float s_med[kL], s_m[kL], s_f[kL];
  __shared__ float mom_s;
  __shared__ double sn[16], sd[16];

  const int b = blockIdx.x;
  const int t = threadIdx.x;
  const int w = t >> 6, lane = t & 63;

  const float sx = scale[b * 2 + 0], sy = scale[b * 2 + 1];
  const float bx = bbox[b * 4 + 0],  by = bbox[b * 4 + 1];

  float loff = lin_off(lane < 7 ? lane : 0);
  int si = 0, sj = 0;
  if (lane < kR2) { si = lane / 7; sj = lane - si * 7; }
  const float offx = __shfl(loff, sj, 64);
  const float offy = __shfl(loff, si, 64);
  const size_t dbase = (size_t)b * (kIMG * kIMG);

  for (int l = w; l < kL; l += 16) {
    float lmx = lmk[(b * kL + l) * 2 + 0];
    float lmy = lmk[(b * kL + l) * 2 + 1];
    float tx = __fsub_rn(lmx, bx);
    tx = __fmul_rn(tx, sx); tx = __fdiv_rn(tx, 224.0f); tx = __fmul_rn(tx, 2.0f);
    float flmx = __fsub_rn(tx, 1.0f);
    float ty = __fsub_rn(lmy, by);
    ty = __fmul_rn(ty, sy); ty = __fdiv_rn(ty, 224.0f); ty = __fmul_rn(ty, 2.0f);
    float flmy = __fsub_rn(ty, 1.0f);

    float v = INFINITY;  // pad lanes sort last; never selected
    if (lane < kR2) {
      float gx = __fadd_rn(flmx, offx);
      float gy = __fadd_rn(flmy, offy);
      float ix = __fmul_rn(__fsub_rn(__fmul_rn(__fadd_rn(gx, 1.0f), 224.0f), 1.0f), 0.5f);
      float iy = __fmul_rn(__fsub_rn(__fmul_rn(__fadd_rn(gy, 1.0f), 224.0f), 1.0f), 0.5f);
      int xi = (int)rintf(ix), yi = (int)rintf(iy);
      bool valid = (xi >= 0) && (xi < kIMG) && (yi >= 0) && (yi < kIMG);
      int xc = min(max(xi, 0), kIMG - 1), yc = min(max(yi, 0), kIMG - 1);
      float dv = depth[dbase + yc * kIMG + xc];
      v = valid ? dv : 0.0f;
    }

    unsigned long long mle = __ballot(lane < kR2 && v <= 1e-4f);
    int cnt = __popcll(mle);

#pragma unroll
    for (int k = 2; k <= 64; k <<= 1) {
#pragma unroll
      for (int j = k >> 1; j > 0; j >>= 1) {
        float ww = __shfl_xor(v, j, 64);
        bool up = ((lane & k) == 0);
        bool lower = ((lane & j) == 0);
        v = (up == lower) ? fminf(v, ww) : fmaxf(v, ww);
      }
    }

    int st = min(max(cnt, 1), kR2 - 1);
    int kk = (st + kR2 - 1) >> 1;        // med_ind in [24,48], wave-uniform
    float m = __shfl(v, kk, 64);
    if (lane == 0) s_med[l] = m;
  }
  __syncthreads();

  if (t < kL) {
    float v = s_med[t];
    int rank = 0;
    for (int j = 0; j < kL; ++j) {
      float vj = s_med[j];
      rank += ((vj < v) || (vj == v && j < t)) ? 1 : 0;
    }
    if (rank == (kL - 1) / 2) mom_s = v;  // lower median, exactly one thread
  }
  __syncthreads();
  if (t < kL) {
    float v = s_med[t];
    s_m[t] = __fmul_rn(v, 500.0f);
    s_f[t] = (fabsf(__fsub_rn(v, mom_s)) < 0.18f) ? 1.0f : 0.0f;
  }
  __syncthreads();

  double pn = 0.0, pd = 0.0;
  for (int g = t; g < kG4; g += 1024) {
    int e = g * 4;                       // e % 4 == 0
    unsigned iu = (unsigned)e / (unsigned)kL;
    int i = (int)iu;
    int j = e - i * kL;                  // j % 4 == 0, j <= 64: no row wrap
    size_t base = (size_t)b * kLL + e;   // 4624 % 4 == 0 -> 16B-aligned
    float4 rp = *(const float4*)(rdp + base);
    float mi = s_m[i], fi = s_f[i];
    float rq[4] = {rp.x, rp.y, rp.z, rp.w};
    float df[4], mk[4];
#pragma unroll
    for (int q = 0; q < 4; ++q) {
      float mj = s_m[j + q], fj = s_f[j + q];
      float diff = __fsub_rn(mi, mj);
      float mv = __fmul_rn(fi, fj);
      df[q] = diff; mk[q] = mv;
      float d = __fsub_rn(rq[q], diff);
      float ad = fabsf(d);
      float le = (ad < 1.0f) ? __fmul_rn(__fmul_rn(0.5f, d), d)
                             : __fsub_rn(ad, 0.5f);
      pn += (double)__fmul_rn(le, mv);
      pd += (double)mv;
    }
    *(float4*)(out_diff + base) = make_float4(df[0], df[1], df[2], df[3]);
    *(float4*)(out_mask + base) = make_float4(mk[0], mk[1], mk[2], mk[3]);
  }

  for (int off = 32; off > 0; off >>= 1) {
    pn += __shfl_down(pn, off, 64);
    pd += __shfl_down(pd, off, 64);
  }
  if (lane == 0) { sn[w] = pn; sd[w] = pd; }
  __syncthreads();
  if (t == 0) {
    double tn = 0.0, td = 0.0;
#pragma unroll
    for (int k = 0; k < 16; ++k) { tn += sn[k]; td += sd[k]; }
    part[2 * b + 0] = tn;
    part[2 * b + 1] = td;
  }
}

__global__ __launch_bounds__(256) void k_final(
    const double* __restrict__ part, float* __restrict__ out0) {
  __shared__ double sn[4], sd[4];
  double pn = 0.0, pd = 0.0;
  for (int i = threadIdx.x; i < kBS; i += 256) {
    pn += part[2 * i + 0];
    pd += part[2 * i + 1];
  }
  for (int off = 32; off > 0; off >>= 1) {
    pn += __shfl_down(pn, off, 64);
    pd += __shfl_down(pd, off, 64);
  }
  int w = threadIdx.x >> 6;
  if ((threadIdx.x & 63) == 0) { sn[w] = pn; sd[w] = pd; }
  __syncthreads();
  if (threadIdx.x == 0) {
    double tn = sn[0] + sn[1] + sn[2] + sn[3];
    double td = sd[0] + sd[1] + sd[2] + sd[3];
    out0[0] = (float)(tn / (td + 1e-4));
  }
}

extern "C" void kernel_launch(void* const* d_in, const int* in_sizes, int n_in,
                              void* d_out, int out_size, void* d_ws, size_t ws_size,
                              hipStream_t stream) {
  const float* rdp   = (const float*)d_in[0];  // [512,68,68]
  const float* depth = (const float*)d_in[1];  // [512,1,224,224]
  const float* lmk   = (const float*)d_in[2];  // [512,68,2]
  const float* scale = (const float*)d_in[3];  // [512,2]
  const float* bbox  = (const float*)d_in[4];  // [512,4]

  float* out = (float*)d_out;
  float* out_diff = out + 1;
  float* out_mask = out + 1 + (size_t)kBS * kLL;

  double* part = (double*)d_ws;                // 512*2*8 = 8192 B

  k_fused<<<dim3(kBS), dim3(1024), 0, stream>>>(depth, lmk, scale, bbox, rdp,
                                                out_diff, out_mask, part);
  k_final<<<dim3(1), dim3(256), 0, stream>>>(part, out);
}